// Round 31
// baseline (174.457 us; speedup 1.0000x reference)
//
#include <hip/hip_runtime.h>

#define NN 100000
#define NE 3200000
#define HD 20
#define EHD 64
#define EOUTD 10
#define TBINS 4096

// ---- radix/counting sort geometry ----
#define EPB 2048
#define NBLKS1 1563                // ceil(NE/EPB)
#define NBINS1 256                 // pass-1 bins: src>>9 in [0,196)
#define N1 (NBINS1 * NBLKS1)       // 400128
#define NBUCK 196
#define WIN 4096
#define WPB 6                      // windows per bucket
#define NWIN (NBUCK * WPB)         // 1176
#define N2 (NBUCK * 512 * WPB)     // 602112
#define KMASK 0x1FFFF              // low 17 bits = dst

// ---------------- scan1: per-1024-block exclusive + block sums ----------
__global__ void scan1_kernel(int* __restrict__ data, int* __restrict__ bsum, int n) {
    __shared__ int s[1024];
    int t = threadIdx.x;
    int i = blockIdx.x * 1024 + t;
    int v = (i < n) ? data[i] : 0;
    s[t] = v;
    __syncthreads();
    for (int off = 1; off < 1024; off <<= 1) {
        int add = (t >= off) ? s[t - off] : 0;
        __syncthreads();
        s[t] += add;
        __syncthreads();
    }
    if (i < n) data[i] = s[t] - v;            // exclusive, block-local
    if (t == 1023) bsum[blockIdx.x] = s[t];
}

// ---------------- scan3f: LDS-scan raw block sums, then add base ---------
__global__ void scan3f_kernel(int* __restrict__ data, const int* __restrict__ bsum,
                              int nb, int n) {
    __shared__ int s[1024];
    int t = threadIdx.x;
    int v = (t < nb) ? bsum[t] : 0;
    s[t] = v;
    __syncthreads();
    for (int off = 1; off < 1024; off <<= 1) {
        int add = (t >= off) ? s[t - off] : 0;
        __syncthreads();
        s[t] += add;
        __syncthreads();
    }
    __syncthreads();
    int i = blockIdx.x * 1024 + t;
    if (i < n) data[i] += s[i >> 10] - ((i >> 10) < nb ? bsum[i >> 10] : 0);
}

// ---------------- scan3bf: same for M2, also emits offsets ---------------
__global__ void scan3bf_kernel(int* __restrict__ data, const int* __restrict__ bsum,
                               int nb, int* __restrict__ offsets) {
    __shared__ int s[1024];
    int t = threadIdx.x;
    int v = (t < nb) ? bsum[t] : 0;
    s[t] = v;
    __syncthreads();
    for (int off = 1; off < 1024; off <<= 1) {
        int add = (t >= off) ? s[t - off] : 0;
        __syncthreads();
        s[t] += add;
        __syncthreads();
    }
    __syncthreads();
    int i = blockIdx.x * 1024 + t;
    if (i >= N2) return;
    int blk = i >> 10;
    int vv = data[i] + s[blk] - (blk < nb ? bsum[blk] : 0);
    data[i] = vv;
    if (i % WPB == 0) {
        int nbidx = i / WPB;                  // = bucket*512 + bin
        if (nbidx <= NN) offsets[nbidx] = vv;
    }
}

// ---------------- pass 1 histogram (bin = src>>9), EPB=2048 --------------
__global__ void hist1_kernel(const int* __restrict__ ei, int* __restrict__ counts1) {
    __shared__ int h[NBINS1];
    int t = threadIdx.x;
    if (t < NBINS1) h[t] = 0;
    __syncthreads();
    int base = blockIdx.x * EPB;
    for (int j = t; j < EPB; j += 512) {
        int e = base + j;
        if (e < NE) atomicAdd(&h[ei[e] >> 9], 1);
    }
    __syncthreads();
    if (t < NBINS1) counts1[t * NBLKS1 + blockIdx.x] = h[t];   // bin-major
}

// ---------------- pass 1 scatter: LDS counting sort, coalesced writeout --
__global__ void scatter1_kernel(const int* __restrict__ ei,
                                const float* __restrict__ ea,
                                const int* __restrict__ counts1s,
                                int2* __restrict__ pk1) {
    __shared__ int2 rec[EPB];                 // 16KB raw records
    __shared__ int2 srt[EPB];                 // 16KB sorted records
    __shared__ unsigned char bin8[EPB];       // 2KB
    __shared__ unsigned char bin8s[EPB];      // 2KB
    __shared__ int hh[NBINS1];                // hist -> cursor
    __shared__ int hbase[NBINS1];             // exclusive base within block
    int t = threadIdx.x;
    int blk = blockIdx.x;
    int base = blk * EPB;
    int n = NE - base; if (n > EPB) n = EPB;

    if (t < NBINS1) hh[t] = 0;
    __syncthreads();

    // load + hist
    for (int j = t; j < n; j += 512) {
        int e = base + j;
        int src = ei[e];
        int b = src >> 9;
        int2 pk;
        pk.x = ei[NE + e] | ((src & 511) << 17);
        pk.y = __float_as_int(ea[e]);
        rec[j] = pk;
        bin8[j] = (unsigned char)b;
        atomicAdd(&hh[b], 1);
    }
    __syncthreads();

    // exclusive scan of 256 bins — ALL threads execute every barrier
    int orig = (t < NBINS1) ? hh[t] : 0;
    if (t < NBINS1) hbase[t] = orig;
    __syncthreads();
    for (int off = 1; off < NBINS1; off <<= 1) {
        int add = (t < NBINS1 && t >= off) ? hbase[t - off] : 0;
        __syncthreads();
        if (t < NBINS1) hbase[t] += add;
        __syncthreads();
    }
    if (t < NBINS1) {
        hbase[t] -= orig;                     // exclusive
        hh[t] = hbase[t];                     // cursor
    }
    __syncthreads();

    // rank + place into sorted LDS
    for (int j = t; j < n; j += 512) {
        int b = bin8[j];
        int pos = atomicAdd(&hh[b], 1);
        srt[pos] = rec[j];
        bin8s[pos] = (unsigned char)b;
    }
    __syncthreads();

    // coalesced write-out: consecutive t in a bin -> consecutive global addrs
    for (int j = t; j < n; j += 512) {
        int b = bin8s[j];
        int gpos = counts1s[b * NBLKS1 + blk] + (j - hbase[b]);
        pk1[gpos] = srt[j];
    }
}

// ---------------- pass 2 histogram (key from pk1.x bits 17+) -------------
__global__ void hist2_kernel(const int2* __restrict__ pk1,
                             const int* __restrict__ counts1s,
                             int* __restrict__ M2) {
    __shared__ int h[512];
    int t = threadIdx.x;
    h[t] = 0; h[t + 256] = 0;
    __syncthreads();
    int b = blockIdx.x / WPB, w = blockIdx.x % WPB;
    int bstart = counts1s[b * NBLKS1];
    int bend;
    if (b + 1 < NBINS1) bend = counts1s[(b + 1) * NBLKS1];
    else bend = NE;
    int start = bstart + w * WIN;
    int end = (start + WIN < bend) ? (start + WIN) : bend;
    for (int i = start + t; i < end; i += 256)
        atomicAdd(&h[(pk1[i].x >> 17) & 511], 1);
    __syncthreads();
    M2[((b * 512) + t) * WPB + w]       = h[t];
    M2[((b * 512) + t + 256) * WPB + w] = h[t + 256];
}

// ---------------- pass 2 scatter: final pos + precompute (ti,fr,idx) ------
__global__ void scatter2_kernel(const int2* __restrict__ pk1,
                                const int* __restrict__ counts1s,
                                const int* __restrict__ M2s,
                                int2* __restrict__ csr_pk) {
    __shared__ int cur[512];
    int t = threadIdx.x;
    int b = blockIdx.x / WPB, w = blockIdx.x % WPB;
    cur[t]       = M2s[((b * 512) + t) * WPB + w];
    cur[t + 256] = M2s[((b * 512) + t + 256) * WPB + w];
    __syncthreads();
    int bstart = counts1s[b * NBLKS1];
    int bend;
    if (b + 1 < NBINS1) bend = counts1s[(b + 1) * NBLKS1];
    else bend = NE;
    int start = bstart + w * WIN;
    int end = (start + WIN < bend) ? (start + WIN) : bend;
    for (int i = start + t; i < end; i += 256) {
        int2 pk = pk1[i];
        int pos = atomicAdd(&cur[(pk.x >> 17) & 511], 1);
        float d = __int_as_float(pk.y);
        int idx = (int)d; if (idx > 9) idx = 9;
        float u = d * ((float)TBINS / 10.0f);
        int ti = (int)u; if (ti > TBINS - 1) ti = TBINS - 1;
        float fr = u - (float)ti;
        int fr16 = (int)(fr * 65536.0f); if (fr16 > 65535) fr16 = 65535;
        pk.x &= KMASK;
        pk.y = fr16 | (ti << 16) | (idx << 28);
        csr_pk[pos] = pk;
    }
}

// ---------------- fused prep: tab rows (blocks 0..15) + xbf2 (rest) ------
__global__ void prep_kernel(const float* __restrict__ W1,
                            const float* __restrict__ b1,
                            const float* __restrict__ W2,
                            const float* __restrict__ b2,
                            const float* __restrict__ x,
                            unsigned short* __restrict__ tab,
                            int* __restrict__ xbf2) {
    const int TBLK = (TBINS + 255) / 256;      // 16 blocks for table
    auto bf16 = [](float f) -> unsigned int {
        unsigned int u = __float_as_uint(f);
        return (u + 0x7fffu + ((u >> 16) & 1u)) >> 16;
    };
    if (blockIdx.x < TBLK) {
        int i = blockIdx.x * 256 + threadIdx.x;
        if (i >= TBINS) return;
        float m0[EOUTD], m1[EOUTD];
        float d0 = (float)i * (10.0f / (float)TBINS);
        float d1 = (float)(i + 1) * (10.0f / (float)TBINS);
        #pragma unroll
        for (int j = 0; j < EOUTD; ++j) { m0[j] = b2[j]; m1[j] = b2[j]; }
        for (int k = 0; k < EHD; ++k) {
            float h0 = fmaxf(fmaf(d0, W1[k], b1[k]), 0.0f);
            float h1 = fmaxf(fmaf(d1, W1[k], b1[k]), 0.0f);
            #pragma unroll
            for (int j = 0; j < EOUTD; ++j) {
                m0[j] = fmaf(h0, W2[k * EOUTD + j], m0[j]);
                m1[j] = fmaf(h1, W2[k * EOUTD + j], m1[j]);
            }
        }
        unsigned short* row = tab + (size_t)i * 32;
        #pragma unroll
        for (int j = 0; j < EOUTD; ++j) {
            row[2 * j]     = (unsigned short)bf16(m0[j]);
            row[2 * j + 1] = (unsigned short)bf16(m1[j] - m0[j]);
        }
        #pragma unroll
        for (int j = 20; j < 32; ++j) row[j] = 0;
    } else {
        int t = (blockIdx.x - TBLK) * 256 + threadIdx.x;
        if (t >= NN * 16) return;
        int node = t >> 4, k = t & 15;
        int v = 0;
        if (k < 10) {
            v = (int)(bf16(x[(size_t)node * 2 * HD + k])
                      | (bf16(x[(size_t)node * 2 * HD + k + 10]) << 16));
        }
        xbf2[t] = v;
    }
}

// ---------------- node-owner kernel: 10 lanes/node, 2 features/lane -------
__launch_bounds__(256)
__global__ void node_kernel(const int* __restrict__ offsets,
                            const int2* __restrict__ csr_pk,
                            const float* __restrict__ x,
                            const int* __restrict__ xbf2,
                            const unsigned short* __restrict__ tab,
                            const float* __restrict__ pa,
                            const float* __restrict__ pb,
                            const float* __restrict__ g1,
                            const float* __restrict__ g2,
                            const float* __restrict__ bias,
                            float* __restrict__ out) {
    int tid  = threadIdx.x;
    int wave = tid >> 6;
    int lane = tid & 63;
    int sub  = lane / 10;                  // 0..5 active, 6 = idle lanes
    int fk   = lane - sub * 10;            // feature pair id 0..9
    int node = blockIdx.x * 24 + wave * 6 + sub;
    bool active = (sub < 6) && (node < NN);

    float a = pa[0], bb = pb[0];
    float oma = 1.0f - a;

    int off0 = 0, deg = 0;
    float xs_lo = 0.0f, xs_hi = 0.0f, axs_lo = 0.0f, axs_hi = 0.0f;
    if (active) {
        off0 = offsets[node];
        deg  = offsets[node + 1] - off0;
        xs_lo = x[(size_t)node * 2 * HD + fk];
        xs_hi = x[(size_t)node * 2 * HD + fk + 10];
        axs_lo = a * xs_lo;
        axs_hi = a * xs_hi;
    }

    float S0a = 0.0f, S1a = 0.0f, Sra = 0.0f;   // feature fk (one-hot)
    float S0b = 0.0f, S1b = 0.0f, Srb = 0.0f;   // feature fk+10 (table)

    auto process = [&](int dst, int dy) {
        int ti  = (dy >> 16) & 0xFFF;
        int idx = (dy >> 28) & 0xF;
        float fr = (float)(dy & 0xFFFF) * (1.0f / 65536.0f);
        unsigned int xw = (unsigned int)xbf2[(((size_t)(unsigned int)dst) << 4) + fk];
        unsigned int tv = *(const unsigned int*)(tab + (((size_t)ti) << 5) + fk * 2);
        float xd_lo = __uint_as_float(xw << 16);
        float xd_hi = __uint_as_float(xw & 0xffff0000u);
        float t0 = fmaf(-oma, xd_lo, axs_lo);
        float t1 = fmaf(-oma, xd_hi, axs_hi);
        float r0 = (t0 != 0.0f)
            ? __builtin_amdgcn_exp2f(bb * __builtin_amdgcn_logf(fabsf(t0))) : 0.0f;
        float r1 = (t1 != 0.0f)
            ? __builtin_amdgcn_exp2f(bb * __builtin_amdgcn_logf(fabsf(t1))) : 0.0f;
        Sra += r0; Srb += r1;
        float c0 = (fk == idx) ? 1.0f : 0.0f;
        float val = __uint_as_float(tv << 16);
        float del = __uint_as_float(tv & 0xffff0000u);
        float c1 = fmaxf(fmaf(fr, del, val), 0.0f);
        S0a += c0; S1a = fmaf(r0, c0, S1a);
        S0b += c1; S1b = fmaf(r1, c1, S1b);
    };

    for (int base = 0; base < deg; base += 10) {
        int nchunk = deg - base; if (nchunk > 10) nchunk = 10;
        // clamped (branch-free) coalesced preload of this chunk's (dst,d)
        int idxc = off0 + base + ((fk < nchunk) ? fk : (nchunk - 1));
        int2 pk = csr_pk[idxc];
        int dstv = pk.x, dbits = pk.y;
        int jj = 0;
        for (; jj + 1 < nchunk; jj += 2) {
            int dA = __shfl(dstv, sub * 10 + jj, 64);
            int bA = __shfl(dbits, sub * 10 + jj, 64);
            int dB = __shfl(dstv, sub * 10 + jj + 1, 64);
            int bB = __shfl(dbits, sub * 10 + jj + 1, 64);
            process(dA, bA);
            process(dB, bB);
        }
        if (jj < nchunk) {
            int dA = __shfl(dstv, sub * 10 + jj, 64);
            int bA = __shfl(dbits, sub * 10 + jj, 64);
            process(dA, bA);
        }
    }

    float sf_lo = (S0a != 0.0f) ? (S1a / S0a) : (0.01f * Sra);
    float sf_hi = (S0b != 0.0f) ? (S1b / S0b) : (0.01f * Srb);

    if (active) {
        // epilogue: lane fk computes output rows fk and fk+10
        float acc0 = bias[fk];
        float acc1 = bias[fk + 10];
        const float* g1r0 = g1 + fk * HD;
        const float* g1r1 = g1 + (fk + 10) * HD;
        const float* g2r0 = g2 + fk * HD;
        const float* g2r1 = g2 + (fk + 10) * HD;
        #pragma unroll
        for (int j = 0; j < 10; ++j) {
            int sl = sub * 10 + j;
            float xj  = __shfl(xs_lo, sl, 64);
            float xj1 = __shfl(xs_hi, sl, 64);
            float sj  = __shfl(sf_lo, sl, 64);
            float sj1 = __shfl(sf_hi, sl, 64);
            acc0 = fmaf(xj, g1r0[j], acc0);  acc0 = fmaf(xj1, g1r0[j + 10], acc0);
            acc0 = fmaf(sj, g2r0[j], acc0);  acc0 = fmaf(sj1, g2r0[j + 10], acc0);
            acc1 = fmaf(xj, g1r1[j], acc1);  acc1 = fmaf(xj1, g1r1[j + 10], acc1);
            acc1 = fmaf(sj, g2r1[j], acc1);  acc1 = fmaf(sj1, g2r1[j + 10], acc1);
        }
        float* op = out + (size_t)node * 2 * HD;
        op[fk]          = fmaxf(acc0, 0.0f);
        op[fk + 10]     = fmaxf(acc1, 0.0f);
        op[HD + fk]     = sf_lo;
        op[HD + fk + 10] = sf_hi;
    }
}

extern "C" void kernel_launch(void* const* d_in, const int* in_sizes, int n_in,
                              void* d_out, int out_size, void* d_ws, size_t ws_size,
                              hipStream_t stream) {
    const float* x    = (const float*)d_in[0];
    const int*   ei   = (const int*)d_in[1];
    const float* ea   = (const float*)d_in[2];
    const float* pa   = (const float*)d_in[3];
    const float* pb   = (const float*)d_in[4];
    const float* g1   = (const float*)d_in[5];
    const float* g2   = (const float*)d_in[6];
    const float* bias = (const float*)d_in[7];
    const float* W1   = (const float*)d_in[8];
    const float* b1   = (const float*)d_in[9];
    const float* W2   = (const float*)d_in[10];
    const float* b2   = (const float*)d_in[11];
    float* out = (float*)d_out;

    // workspace layout (all segments 128B-aligned)
    char* ws = (char*)d_ws;
    int*   counts1 = (int*)ws;     ws += ((size_t)N1 * 4 + 127) / 128 * 128;
    int*   bsum1   = (int*)ws;     ws += (1024 * 4 + 127) / 128 * 128;
    int*   M2      = (int*)ws;     ws += ((size_t)N2 * 4 + 127) / 128 * 128;
    int*   bsum2   = (int*)ws;     ws += (1024 * 4 + 127) / 128 * 128;
    int*   offsets = (int*)ws;     ws += ((size_t)(NN + 1) * 4 + 127) / 128 * 128;
    int2*  pk1     = (int2*)ws;    ws += (size_t)NE * 8;
    int2*  csr_pk  = (int2*)ws;    ws += (size_t)NE * 8;
    unsigned short* tab = (unsigned short*)ws;   ws += ((size_t)TBINS * 32 * 2 + 127) / 128 * 128;
    int*   xbf2    = (int*)ws;     ws += ((size_t)NN * 16 * 4 + 127) / 128 * 128;

    const int TBLK = (TBINS + 255) / 256;
    prep_kernel<<<TBLK + (NN * 16 + 255) / 256, 256, 0, stream>>>(W1, b1, W2, b2, x,
                                                                  tab, xbf2);

    // pass 1: group by bucket (src>>9), LDS-sorted coalesced scatter
    const int nb1 = (N1 + 1023) / 1024;
    hist1_kernel<<<NBLKS1, 512, 0, stream>>>(ei, counts1);
    scan1_kernel<<<nb1, 1024, 0, stream>>>(counts1, bsum1, N1);
    scan3f_kernel<<<nb1, 1024, 0, stream>>>(counts1, bsum1, nb1, N1);
    scatter1_kernel<<<NBLKS1, 512, 0, stream>>>(ei, ea, counts1, pk1);

    // pass 2: within bucket, bin = src & 511 (== exact node)
    const int nb2 = (N2 + 1023) / 1024;
    hist2_kernel<<<NWIN, 256, 0, stream>>>(pk1, counts1, M2);
    scan1_kernel<<<nb2, 1024, 0, stream>>>(M2, bsum2, N2);
    scan3bf_kernel<<<nb2, 1024, 0, stream>>>(M2, bsum2, nb2, offsets);
    scatter2_kernel<<<NWIN, 256, 0, stream>>>(pk1, counts1, M2, csr_pk);

    node_kernel<<<(NN + 23) / 24, 256, 0, stream>>>(offsets, csr_pk, x, xbf2, tab,
                                                    pa, pb, g1, g2, bias, out);
}

// Round 32
// 168.045 us; speedup vs baseline: 1.0382x; 1.0382x over previous
//
#include <hip/hip_runtime.h>

#define NN 100000
#define NE 3200000
#define HD 20
#define EHD 64
#define EOUTD 10
#define TBINS 4096

// ---- radix/counting sort geometry ----
#define EPB 2048
#define NBLKS1 1563                // ceil(NE/EPB)
#define NBINS1 256                 // pass-1 bins: src>>9 in [0,196)
#define N1 (NBINS1 * NBLKS1)       // 400128
#define NBUCK 196
#define WIN 4096
#define WPB 6                      // windows per bucket
#define NWIN (NBUCK * WPB)         // 1176
#define N2 (NBUCK * 512 * WPB)     // 602112
#define KMASK 0x1FFFF              // low 17 bits = dst

// ---------------- scan1: per-1024-block exclusive + block sums ----------
__global__ void scan1_kernel(int* __restrict__ data, int* __restrict__ bsum, int n) {
    __shared__ int s[1024];
    int t = threadIdx.x;
    int i = blockIdx.x * 1024 + t;
    int v = (i < n) ? data[i] : 0;
    s[t] = v;
    __syncthreads();
    for (int off = 1; off < 1024; off <<= 1) {
        int add = (t >= off) ? s[t - off] : 0;
        __syncthreads();
        s[t] += add;
        __syncthreads();
    }
    if (i < n) data[i] = s[t] - v;            // exclusive, block-local
    if (t == 1023) bsum[blockIdx.x] = s[t];
}

// ---------------- scan3f: LDS-scan raw block sums, then add base ---------
__global__ void scan3f_kernel(int* __restrict__ data, const int* __restrict__ bsum,
                              int nb, int n) {
    __shared__ int s[1024];
    int t = threadIdx.x;
    int v = (t < nb) ? bsum[t] : 0;
    s[t] = v;
    __syncthreads();
    for (int off = 1; off < 1024; off <<= 1) {
        int add = (t >= off) ? s[t - off] : 0;
        __syncthreads();
        s[t] += add;
        __syncthreads();
    }
    __syncthreads();
    int i = blockIdx.x * 1024 + t;
    if (i < n) data[i] += s[i >> 10] - ((i >> 10) < nb ? bsum[i >> 10] : 0);
}

// ---------------- scan3bf: same for M2, also emits offsets ---------------
__global__ void scan3bf_kernel(int* __restrict__ data, const int* __restrict__ bsum,
                               int nb, int* __restrict__ offsets) {
    __shared__ int s[1024];
    int t = threadIdx.x;
    int v = (t < nb) ? bsum[t] : 0;
    s[t] = v;
    __syncthreads();
    for (int off = 1; off < 1024; off <<= 1) {
        int add = (t >= off) ? s[t - off] : 0;
        __syncthreads();
        s[t] += add;
        __syncthreads();
    }
    __syncthreads();
    int i = blockIdx.x * 1024 + t;
    if (i >= N2) return;
    int blk = i >> 10;
    int vv = data[i] + s[blk] - (blk < nb ? bsum[blk] : 0);
    data[i] = vv;
    if (i % WPB == 0) {
        int nbidx = i / WPB;                  // = bucket*512 + bin
        if (nbidx <= NN) offsets[nbidx] = vv;
    }
}

// ---------------- pass 1 scatter: LDS counting sort, coalesced writeout --
__global__ void scatter1_kernel(const int* __restrict__ ei,
                                const float* __restrict__ ea,
                                const int* __restrict__ counts1s,
                                int2* __restrict__ pk1) {
    __shared__ int2 rec[EPB];                 // 16KB raw records
    __shared__ int2 srt[EPB];                 // 16KB sorted records
    __shared__ unsigned char bin8[EPB];       // 2KB
    __shared__ unsigned char bin8s[EPB];      // 2KB
    __shared__ int hh[NBINS1];                // hist -> cursor
    __shared__ int hbase[NBINS1];             // exclusive base within block
    int t = threadIdx.x;
    int blk = blockIdx.x;
    int base = blk * EPB;
    int n = NE - base; if (n > EPB) n = EPB;

    if (t < NBINS1) hh[t] = 0;
    __syncthreads();

    // load + hist
    for (int j = t; j < n; j += 512) {
        int e = base + j;
        int src = ei[e];
        int b = src >> 9;
        int2 pk;
        pk.x = ei[NE + e] | ((src & 511) << 17);
        pk.y = __float_as_int(ea[e]);
        rec[j] = pk;
        bin8[j] = (unsigned char)b;
        atomicAdd(&hh[b], 1);
    }
    __syncthreads();

    // exclusive scan of 256 bins — ALL threads execute every barrier
    int orig = (t < NBINS1) ? hh[t] : 0;
    if (t < NBINS1) hbase[t] = orig;
    __syncthreads();
    for (int off = 1; off < NBINS1; off <<= 1) {
        int add = (t < NBINS1 && t >= off) ? hbase[t - off] : 0;
        __syncthreads();
        if (t < NBINS1) hbase[t] += add;
        __syncthreads();
    }
    if (t < NBINS1) {
        hbase[t] -= orig;                     // exclusive
        hh[t] = hbase[t];                     // cursor
    }
    __syncthreads();

    // rank + place into sorted LDS
    for (int j = t; j < n; j += 512) {
        int b = bin8[j];
        int pos = atomicAdd(&hh[b], 1);
        srt[pos] = rec[j];
        bin8s[pos] = (unsigned char)b;
    }
    __syncthreads();

    // coalesced write-out: consecutive t in a bin -> consecutive global addrs
    for (int j = t; j < n; j += 512) {
        int b = bin8s[j];
        int gpos = counts1s[b * NBLKS1 + blk] + (j - hbase[b]);
        pk1[gpos] = srt[j];
    }
}

// ---------------- pass 2 histogram (key from pk1.x bits 17+) -------------
__global__ void hist2_kernel(const int2* __restrict__ pk1,
                             const int* __restrict__ counts1s,
                             int* __restrict__ M2) {
    __shared__ int h[512];
    int t = threadIdx.x;
    h[t] = 0; h[t + 256] = 0;
    __syncthreads();
    int b = blockIdx.x / WPB, w = blockIdx.x % WPB;
    int bstart = counts1s[b * NBLKS1];
    int bend;
    if (b + 1 < NBINS1) bend = counts1s[(b + 1) * NBLKS1];
    else bend = NE;
    int start = bstart + w * WIN;
    int end = (start + WIN < bend) ? (start + WIN) : bend;
    for (int i = start + t; i < end; i += 256)
        atomicAdd(&h[(pk1[i].x >> 17) & 511], 1);
    __syncthreads();
    M2[((b * 512) + t) * WPB + w]       = h[t];
    M2[((b * 512) + t + 256) * WPB + w] = h[t + 256];
}

// ---------------- pass 2 scatter: final pos + precompute (ti,fr,idx) ------
__global__ void scatter2_kernel(const int2* __restrict__ pk1,
                                const int* __restrict__ counts1s,
                                const int* __restrict__ M2s,
                                int2* __restrict__ csr_pk) {
    __shared__ int cur[512];
    int t = threadIdx.x;
    int b = blockIdx.x / WPB, w = blockIdx.x % WPB;
    cur[t]       = M2s[((b * 512) + t) * WPB + w];
    cur[t + 256] = M2s[((b * 512) + t + 256) * WPB + w];
    __syncthreads();
    int bstart = counts1s[b * NBLKS1];
    int bend;
    if (b + 1 < NBINS1) bend = counts1s[(b + 1) * NBLKS1];
    else bend = NE;
    int start = bstart + w * WIN;
    int end = (start + WIN < bend) ? (start + WIN) : bend;
    for (int i = start + t; i < end; i += 256) {
        int2 pk = pk1[i];
        int pos = atomicAdd(&cur[(pk.x >> 17) & 511], 1);
        float d = __int_as_float(pk.y);
        int idx = (int)d; if (idx > 9) idx = 9;
        float u = d * ((float)TBINS / 10.0f);
        int ti = (int)u; if (ti > TBINS - 1) ti = TBINS - 1;
        float fr = u - (float)ti;
        int fr16 = (int)(fr * 65536.0f); if (fr16 > 65535) fr16 = 65535;
        pk.x &= KMASK;
        pk.y = fr16 | (ti << 16) | (idx << 28);
        csr_pk[pos] = pk;
    }
}

// ---------------- fused prep: tab (16 blks) + xbf2 (3907 blks) + hist1 ---
// xbf2 packed rows: [NN][10] ints = 4.0MB (L2-resident)
#define XBLK ((NN * 10 + 255) / 256)
__global__ void prep_kernel(const float* __restrict__ W1,
                            const float* __restrict__ b1,
                            const float* __restrict__ W2,
                            const float* __restrict__ b2,
                            const float* __restrict__ x,
                            const int* __restrict__ ei,
                            unsigned short* __restrict__ tab,
                            int* __restrict__ xbf2,
                            int* __restrict__ counts1) {
    const int TBLK = (TBINS + 255) / 256;      // 16 blocks for table
    auto bf16 = [](float f) -> unsigned int {
        unsigned int u = __float_as_uint(f);
        return (u + 0x7fffu + ((u >> 16) & 1u)) >> 16;
    };
    if (blockIdx.x < TBLK) {
        int i = blockIdx.x * 256 + threadIdx.x;
        if (i >= TBINS) return;
        float m0[EOUTD], m1[EOUTD];
        float d0 = (float)i * (10.0f / (float)TBINS);
        float d1 = (float)(i + 1) * (10.0f / (float)TBINS);
        #pragma unroll
        for (int j = 0; j < EOUTD; ++j) { m0[j] = b2[j]; m1[j] = b2[j]; }
        for (int k = 0; k < EHD; ++k) {
            float h0 = fmaxf(fmaf(d0, W1[k], b1[k]), 0.0f);
            float h1 = fmaxf(fmaf(d1, W1[k], b1[k]), 0.0f);
            #pragma unroll
            for (int j = 0; j < EOUTD; ++j) {
                m0[j] = fmaf(h0, W2[k * EOUTD + j], m0[j]);
                m1[j] = fmaf(h1, W2[k * EOUTD + j], m1[j]);
            }
        }
        unsigned short* row = tab + (size_t)i * 32;
        #pragma unroll
        for (int j = 0; j < EOUTD; ++j) {
            row[2 * j]     = (unsigned short)bf16(m0[j]);
            row[2 * j + 1] = (unsigned short)bf16(m1[j] - m0[j]);
        }
        #pragma unroll
        for (int j = 20; j < 32; ++j) row[j] = 0;
    } else if (blockIdx.x < TBLK + XBLK) {
        int t = (blockIdx.x - TBLK) * 256 + threadIdx.x;
        if (t >= NN * 10) return;
        int node = t / 10;
        int k = t - node * 10;
        xbf2[t] = (int)(bf16(x[(size_t)node * 2 * HD + k])
                        | (bf16(x[(size_t)node * 2 * HD + k + 10]) << 16));
    } else {
        // hist1: bin = src>>9
        __shared__ int h[NBINS1];
        int t = threadIdx.x;
        int blk = blockIdx.x - TBLK - XBLK;
        h[t] = 0;
        __syncthreads();
        int base = blk * EPB;
        for (int j = t; j < EPB; j += 256) {
            int e = base + j;
            if (e < NE) atomicAdd(&h[ei[e] >> 9], 1);
        }
        __syncthreads();
        counts1[t * NBLKS1 + blk] = h[t];      // bin-major
    }
}

// ---------------- node-owner kernel: 10 lanes/node, 2 features/lane -------
__launch_bounds__(256)
__global__ void node_kernel(const int* __restrict__ offsets,
                            const int2* __restrict__ csr_pk,
                            const float* __restrict__ x,
                            const int* __restrict__ xbf2,
                            const unsigned short* __restrict__ tab,
                            const float* __restrict__ pa,
                            const float* __restrict__ pb,
                            const float* __restrict__ g1,
                            const float* __restrict__ g2,
                            const float* __restrict__ bias,
                            float* __restrict__ out) {
    int tid  = threadIdx.x;
    int wave = tid >> 6;
    int lane = tid & 63;
    int sub  = lane / 10;                  // 0..5 active, 6 = idle lanes
    int fk   = lane - sub * 10;            // feature pair id 0..9
    int node = blockIdx.x * 24 + wave * 6 + sub;
    bool active = (sub < 6) && (node < NN);

    float a = pa[0], bb = pb[0];
    float oma = 1.0f - a;

    int off0 = 0, deg = 0;
    float xs_lo = 0.0f, xs_hi = 0.0f, axs_lo = 0.0f, axs_hi = 0.0f;
    if (active) {
        off0 = offsets[node];
        deg  = offsets[node + 1] - off0;
        xs_lo = x[(size_t)node * 2 * HD + fk];
        xs_hi = x[(size_t)node * 2 * HD + fk + 10];
        axs_lo = a * xs_lo;
        axs_hi = a * xs_hi;
    }

    float S0a = 0.0f, S1a = 0.0f, Sra = 0.0f;   // feature fk (one-hot)
    float S0b = 0.0f, S1b = 0.0f, Srb = 0.0f;   // feature fk+10 (table)

    auto process = [&](int dst, int dy) {
        int ti  = (dy >> 16) & 0xFFF;
        int idx = (dy >> 28) & 0xF;
        float fr = (float)(dy & 0xFFFF) * (1.0f / 65536.0f);
        unsigned int xw = (unsigned int)xbf2[(size_t)(unsigned int)dst * 10 + fk];
        unsigned int tv = *(const unsigned int*)(tab + (((size_t)ti) << 5) + fk * 2);
        float xd_lo = __uint_as_float(xw << 16);
        float xd_hi = __uint_as_float(xw & 0xffff0000u);
        float t0 = fmaf(-oma, xd_lo, axs_lo);
        float t1 = fmaf(-oma, xd_hi, axs_hi);
        float r0 = (t0 != 0.0f)
            ? __builtin_amdgcn_exp2f(bb * __builtin_amdgcn_logf(fabsf(t0))) : 0.0f;
        float r1 = (t1 != 0.0f)
            ? __builtin_amdgcn_exp2f(bb * __builtin_amdgcn_logf(fabsf(t1))) : 0.0f;
        Sra += r0; Srb += r1;
        float c0 = (fk == idx) ? 1.0f : 0.0f;
        float val = __uint_as_float(tv << 16);
        float del = __uint_as_float(tv & 0xffff0000u);
        float c1 = fmaxf(fmaf(fr, del, val), 0.0f);
        S0a += c0; S1a = fmaf(r0, c0, S1a);
        S0b += c1; S1b = fmaf(r1, c1, S1b);
    };

    for (int base = 0; base < deg; base += 10) {
        int nchunk = deg - base; if (nchunk > 10) nchunk = 10;
        // clamped (branch-free) coalesced preload of this chunk's (dst,d)
        int idxc = off0 + base + ((fk < nchunk) ? fk : (nchunk - 1));
        int2 pk = csr_pk[idxc];
        int dstv = pk.x, dbits = pk.y;
        int jj = 0;
        for (; jj + 1 < nchunk; jj += 2) {
            int dA = __shfl(dstv, sub * 10 + jj, 64);
            int bA = __shfl(dbits, sub * 10 + jj, 64);
            int dB = __shfl(dstv, sub * 10 + jj + 1, 64);
            int bB = __shfl(dbits, sub * 10 + jj + 1, 64);
            process(dA, bA);
            process(dB, bB);
        }
        if (jj < nchunk) {
            int dA = __shfl(dstv, sub * 10 + jj, 64);
            int bA = __shfl(dbits, sub * 10 + jj, 64);
            process(dA, bA);
        }
    }

    float sf_lo = (S0a != 0.0f) ? (S1a / S0a) : (0.01f * Sra);
    float sf_hi = (S0b != 0.0f) ? (S1b / S0b) : (0.01f * Srb);

    if (active) {
        // epilogue: lane fk computes output rows fk and fk+10
        float acc0 = bias[fk];
        float acc1 = bias[fk + 10];
        const float* g1r0 = g1 + fk * HD;
        const float* g1r1 = g1 + (fk + 10) * HD;
        const float* g2r0 = g2 + fk * HD;
        const float* g2r1 = g2 + (fk + 10) * HD;
        #pragma unroll
        for (int j = 0; j < 10; ++j) {
            int sl = sub * 10 + j;
            float xj  = __shfl(xs_lo, sl, 64);
            float xj1 = __shfl(xs_hi, sl, 64);
            float sj  = __shfl(sf_lo, sl, 64);
            float sj1 = __shfl(sf_hi, sl, 64);
            acc0 = fmaf(xj, g1r0[j], acc0);  acc0 = fmaf(xj1, g1r0[j + 10], acc0);
            acc0 = fmaf(sj, g2r0[j], acc0);  acc0 = fmaf(sj1, g2r0[j + 10], acc0);
            acc1 = fmaf(xj, g1r1[j], acc1);  acc1 = fmaf(xj1, g1r1[j + 10], acc1);
            acc1 = fmaf(sj, g2r1[j], acc1);  acc1 = fmaf(sj1, g2r1[j + 10], acc1);
        }
        float* op = out + (size_t)node * 2 * HD;
        op[fk]          = fmaxf(acc0, 0.0f);
        op[fk + 10]     = fmaxf(acc1, 0.0f);
        op[HD + fk]     = sf_lo;
        op[HD + fk + 10] = sf_hi;
    }
}

extern "C" void kernel_launch(void* const* d_in, const int* in_sizes, int n_in,
                              void* d_out, int out_size, void* d_ws, size_t ws_size,
                              hipStream_t stream) {
    const float* x    = (const float*)d_in[0];
    const int*   ei   = (const int*)d_in[1];
    const float* ea   = (const float*)d_in[2];
    const float* pa   = (const float*)d_in[3];
    const float* pb   = (const float*)d_in[4];
    const float* g1   = (const float*)d_in[5];
    const float* g2   = (const float*)d_in[6];
    const float* bias = (const float*)d_in[7];
    const float* W1   = (const float*)d_in[8];
    const float* b1   = (const float*)d_in[9];
    const float* W2   = (const float*)d_in[10];
    const float* b2   = (const float*)d_in[11];
    float* out = (float*)d_out;

    // workspace layout (all segments 128B-aligned)
    char* ws = (char*)d_ws;
    int*   counts1 = (int*)ws;     ws += ((size_t)N1 * 4 + 127) / 128 * 128;
    int*   bsum1   = (int*)ws;     ws += (1024 * 4 + 127) / 128 * 128;
    int*   M2      = (int*)ws;     ws += ((size_t)N2 * 4 + 127) / 128 * 128;
    int*   bsum2   = (int*)ws;     ws += (1024 * 4 + 127) / 128 * 128;
    int*   offsets = (int*)ws;     ws += ((size_t)(NN + 1) * 4 + 127) / 128 * 128;
    int2*  pk1     = (int2*)ws;    ws += (size_t)NE * 8;
    int2*  csr_pk  = (int2*)ws;    ws += (size_t)NE * 8;
    unsigned short* tab = (unsigned short*)ws;   ws += ((size_t)TBINS * 32 * 2 + 127) / 128 * 128;
    int*   xbf2    = (int*)ws;     ws += ((size_t)NN * 10 * 4 + 127) / 128 * 128;

    const int TBLK = (TBINS + 255) / 256;
    prep_kernel<<<TBLK + XBLK + NBLKS1, 256, 0, stream>>>(W1, b1, W2, b2, x, ei,
                                                          tab, xbf2, counts1);

    // pass 1: group by bucket (src>>9), LDS-sorted coalesced scatter
    const int nb1 = (N1 + 1023) / 1024;
    scan1_kernel<<<nb1, 1024, 0, stream>>>(counts1, bsum1, N1);
    scan3f_kernel<<<nb1, 1024, 0, stream>>>(counts1, bsum1, nb1, N1);
    scatter1_kernel<<<NBLKS1, 512, 0, stream>>>(ei, ea, counts1, pk1);

    // pass 2: within bucket, bin = src & 511 (== exact node)
    const int nb2 = (N2 + 1023) / 1024;
    hist2_kernel<<<NWIN, 256, 0, stream>>>(pk1, counts1, M2);
    scan1_kernel<<<nb2, 1024, 0, stream>>>(M2, bsum2, N2);
    scan3bf_kernel<<<nb2, 1024, 0, stream>>>(M2, bsum2, nb2, offsets);
    scatter2_kernel<<<NWIN, 256, 0, stream>>>(pk1, counts1, M2, csr_pk);

    node_kernel<<<(NN + 23) / 24, 256, 0, stream>>>(offsets, csr_pk, x, xbf2, tab,
                                                    pa, pb, g1, g2, bias, out);
}

// Round 33
// 139.945 us; speedup vs baseline: 1.2466x; 1.2008x over previous
//
#include <hip/hip_runtime.h>

#define NN 100000
#define NE 3200000
#define HD 20
#define EHD 64
#define EOUTD 10
#define TBINS 4096

// ---- radix/counting sort geometry ----
#define EPB 2048
#define NBLKS1 1563                // ceil(NE/EPB)
#define NBINS1 256                 // pass-1 bins: src>>9 in [0,196)
#define N1 (NBINS1 * NBLKS1)       // 400128
#define NBUCK 196
#define KMASK 0x1FFFF              // low 17 bits = dst

// ---------------- scan1: per-1024-block exclusive + block sums ----------
__global__ void scan1_kernel(int* __restrict__ data, int* __restrict__ bsum, int n) {
    __shared__ int s[1024];
    int t = threadIdx.x;
    int i = blockIdx.x * 1024 + t;
    int v = (i < n) ? data[i] : 0;
    s[t] = v;
    __syncthreads();
    for (int off = 1; off < 1024; off <<= 1) {
        int add = (t >= off) ? s[t - off] : 0;
        __syncthreads();
        s[t] += add;
        __syncthreads();
    }
    if (i < n) data[i] = s[t] - v;            // exclusive, block-local
    if (t == 1023) bsum[blockIdx.x] = s[t];
}

// ---------------- scan3f: LDS-scan raw block sums, then add base ---------
__global__ void scan3f_kernel(int* __restrict__ data, const int* __restrict__ bsum,
                              int nb, int n) {
    __shared__ int s[1024];
    int t = threadIdx.x;
    int v = (t < nb) ? bsum[t] : 0;
    s[t] = v;
    __syncthreads();
    for (int off = 1; off < 1024; off <<= 1) {
        int add = (t >= off) ? s[t - off] : 0;
        __syncthreads();
        s[t] += add;
        __syncthreads();
    }
    __syncthreads();
    int i = blockIdx.x * 1024 + t;
    if (i < n) data[i] += s[i >> 10] - ((i >> 10) < nb ? bsum[i >> 10] : 0);
}

// ---------------- pass 1 scatter: LDS counting sort, coalesced writeout --
__global__ void scatter1_kernel(const int* __restrict__ ei,
                                const float* __restrict__ ea,
                                const int* __restrict__ counts1s,
                                int2* __restrict__ pk1) {
    __shared__ int2 rec[EPB];                 // 16KB raw records
    __shared__ int2 srt[EPB];                 // 16KB sorted records
    __shared__ unsigned char bin8[EPB];       // 2KB
    __shared__ unsigned char bin8s[EPB];      // 2KB
    __shared__ int hh[NBINS1];                // hist -> cursor
    __shared__ int hbase[NBINS1];             // exclusive base within block
    int t = threadIdx.x;
    int blk = blockIdx.x;
    int base = blk * EPB;
    int n = NE - base; if (n > EPB) n = EPB;

    if (t < NBINS1) hh[t] = 0;
    __syncthreads();

    // load + hist
    for (int j = t; j < n; j += 512) {
        int e = base + j;
        int src = ei[e];
        int b = src >> 9;
        int2 pk;
        pk.x = ei[NE + e] | ((src & 511) << 17);
        pk.y = __float_as_int(ea[e]);
        rec[j] = pk;
        bin8[j] = (unsigned char)b;
        atomicAdd(&hh[b], 1);
    }
    __syncthreads();

    // exclusive scan of 256 bins — ALL threads execute every barrier
    int orig = (t < NBINS1) ? hh[t] : 0;
    if (t < NBINS1) hbase[t] = orig;
    __syncthreads();
    for (int off = 1; off < NBINS1; off <<= 1) {
        int add = (t < NBINS1 && t >= off) ? hbase[t - off] : 0;
        __syncthreads();
        if (t < NBINS1) hbase[t] += add;
        __syncthreads();
    }
    if (t < NBINS1) {
        hbase[t] -= orig;                     // exclusive
        hh[t] = hbase[t];                     // cursor
    }
    __syncthreads();

    // rank + place into sorted LDS
    for (int j = t; j < n; j += 512) {
        int b = bin8[j];
        int pos = atomicAdd(&hh[b], 1);
        srt[pos] = rec[j];
        bin8s[pos] = (unsigned char)b;
    }
    __syncthreads();

    // coalesced write-out: consecutive t in a bin -> consecutive global addrs
    for (int j = t; j < n; j += 512) {
        int b = bin8s[j];
        int gpos = counts1s[b * NBLKS1 + blk] + (j - hbase[b]);
        pk1[gpos] = srt[j];
    }
}

// ---------------- fused pass 2: hist + scan + offsets + scatter ----------
// one block per bucket (512 nodes); 1024 threads
__global__ void pass2_kernel(const int2* __restrict__ pk1,
                             const int* __restrict__ counts1s,
                             int* __restrict__ offsets,
                             int2* __restrict__ csr_pk) {
    __shared__ int h[512];
    __shared__ int hb[512];
    int t = threadIdx.x;
    int b = blockIdx.x;
    if (t < 512) h[t] = 0;
    __syncthreads();
    int bstart = counts1s[b * NBLKS1];
    int bend   = counts1s[(b + 1) * NBLKS1];   // bin 196..255 rows exist (empty)
    // hist of 9-bit keys
    for (int i = bstart + t; i < bend; i += 1024)
        atomicAdd(&h[(pk1[i].x >> 17) & 511], 1);
    __syncthreads();
    // exclusive scan of 512 bins — ALL threads execute every barrier
    int orig = (t < 512) ? h[t] : 0;
    if (t < 512) hb[t] = orig;
    __syncthreads();
    for (int off = 1; off < 512; off <<= 1) {
        int add = (t < 512 && t >= off) ? hb[t - off] : 0;
        __syncthreads();
        if (t < 512) hb[t] += add;
        __syncthreads();
    }
    if (t < 512) {
        hb[t] -= orig;                        // exclusive within bucket
        h[t] = bstart + hb[t];                // global cursor
        int node = b * 512 + t;
        if (node <= NN) offsets[node] = bstart + hb[t];
    }
    __syncthreads();
    // place with precompute (ti, fr, idx) packed into pk.y
    for (int i = bstart + t; i < bend; i += 1024) {
        int2 pk = pk1[i];
        int pos = atomicAdd(&h[(pk.x >> 17) & 511], 1);
        float d = __int_as_float(pk.y);
        int idx = (int)d; if (idx > 9) idx = 9;
        float u = d * ((float)TBINS / 10.0f);
        int ti = (int)u; if (ti > TBINS - 1) ti = TBINS - 1;
        float fr = u - (float)ti;
        int fr16 = (int)(fr * 65536.0f); if (fr16 > 65535) fr16 = 65535;
        pk.x &= KMASK;
        pk.y = fr16 | (ti << 16) | (idx << 28);
        csr_pk[pos] = pk;
    }
}

// ---------------- fused prep: tab (16 blks) + xbf2 (3907 blks) + hist1 ---
#define XBLK ((NN * 10 + 255) / 256)
__global__ void prep_kernel(const float* __restrict__ W1,
                            const float* __restrict__ b1,
                            const float* __restrict__ W2,
                            const float* __restrict__ b2,
                            const float* __restrict__ x,
                            const int* __restrict__ ei,
                            unsigned short* __restrict__ tab,
                            int* __restrict__ xbf2,
                            int* __restrict__ counts1) {
    const int TBLK = (TBINS + 255) / 256;      // 16 blocks for table
    auto bf16 = [](float f) -> unsigned int {
        unsigned int u = __float_as_uint(f);
        return (u + 0x7fffu + ((u >> 16) & 1u)) >> 16;
    };
    if (blockIdx.x < TBLK) {
        int i = blockIdx.x * 256 + threadIdx.x;
        if (i >= TBINS) return;
        float m0[EOUTD], m1[EOUTD];
        float d0 = (float)i * (10.0f / (float)TBINS);
        float d1 = (float)(i + 1) * (10.0f / (float)TBINS);
        #pragma unroll
        for (int j = 0; j < EOUTD; ++j) { m0[j] = b2[j]; m1[j] = b2[j]; }
        for (int k = 0; k < EHD; ++k) {
            float h0 = fmaxf(fmaf(d0, W1[k], b1[k]), 0.0f);
            float h1 = fmaxf(fmaf(d1, W1[k], b1[k]), 0.0f);
            #pragma unroll
            for (int j = 0; j < EOUTD; ++j) {
                m0[j] = fmaf(h0, W2[k * EOUTD + j], m0[j]);
                m1[j] = fmaf(h1, W2[k * EOUTD + j], m1[j]);
            }
        }
        unsigned short* row = tab + (size_t)i * 32;
        #pragma unroll
        for (int j = 0; j < EOUTD; ++j) {
            row[2 * j]     = (unsigned short)bf16(m0[j]);
            row[2 * j + 1] = (unsigned short)bf16(m1[j] - m0[j]);
        }
        #pragma unroll
        for (int j = 20; j < 32; ++j) row[j] = 0;
    } else if (blockIdx.x < TBLK + XBLK) {
        int t = (blockIdx.x - TBLK) * 256 + threadIdx.x;
        if (t >= NN * 10) return;
        int node = t / 10;
        int k = t - node * 10;
        xbf2[t] = (int)(bf16(x[(size_t)node * 2 * HD + k])
                        | (bf16(x[(size_t)node * 2 * HD + k + 10]) << 16));
    } else {
        // hist1: bin = src>>9
        __shared__ int h[NBINS1];
        int t = threadIdx.x;
        int blk = blockIdx.x - TBLK - XBLK;
        h[t] = 0;
        __syncthreads();
        int base = blk * EPB;
        for (int j = t; j < EPB; j += 256) {
            int e = base + j;
            if (e < NE) atomicAdd(&h[ei[e] >> 9], 1);
        }
        __syncthreads();
        counts1[t * NBLKS1 + blk] = h[t];      // bin-major
    }
}

// ---------------- node-owner kernel: 10 lanes/node, 2 features/lane -------
__launch_bounds__(256)
__global__ void node_kernel(const int* __restrict__ offsets,
                            const int2* __restrict__ csr_pk,
                            const float* __restrict__ x,
                            const int* __restrict__ xbf2,
                            const unsigned short* __restrict__ tab,
                            const float* __restrict__ pa,
                            const float* __restrict__ pb,
                            const float* __restrict__ g1,
                            const float* __restrict__ g2,
                            const float* __restrict__ bias,
                            float* __restrict__ out) {
    int tid  = threadIdx.x;
    int wave = tid >> 6;
    int lane = tid & 63;
    int sub  = lane / 10;                  // 0..5 active, 6 = idle lanes
    int fk   = lane - sub * 10;            // feature pair id 0..9
    int node = blockIdx.x * 24 + wave * 6 + sub;
    bool active = (sub < 6) && (node < NN);

    float a = pa[0], bb = pb[0];
    float oma = 1.0f - a;

    int off0 = 0, deg = 0;
    float xs_lo = 0.0f, xs_hi = 0.0f, axs_lo = 0.0f, axs_hi = 0.0f;
    if (active) {
        off0 = offsets[node];
        deg  = offsets[node + 1] - off0;
        xs_lo = x[(size_t)node * 2 * HD + fk];
        xs_hi = x[(size_t)node * 2 * HD + fk + 10];
        axs_lo = a * xs_lo;
        axs_hi = a * xs_hi;
    }

    float S0a = 0.0f, S1a = 0.0f, Sra = 0.0f;   // feature fk (one-hot)
    float S0b = 0.0f, S1b = 0.0f, Srb = 0.0f;   // feature fk+10 (table)

    auto process = [&](int dst, int dy) {
        int ti  = (dy >> 16) & 0xFFF;
        int idx = (dy >> 28) & 0xF;
        float fr = (float)(dy & 0xFFFF) * (1.0f / 65536.0f);
        unsigned int xw = (unsigned int)xbf2[(size_t)(unsigned int)dst * 10 + fk];
        unsigned int tv = *(const unsigned int*)(tab + (((size_t)ti) << 5) + fk * 2);
        float xd_lo = __uint_as_float(xw << 16);
        float xd_hi = __uint_as_float(xw & 0xffff0000u);
        float t0 = fmaf(-oma, xd_lo, axs_lo);
        float t1 = fmaf(-oma, xd_hi, axs_hi);
        float r0 = (t0 != 0.0f)
            ? __builtin_amdgcn_exp2f(bb * __builtin_amdgcn_logf(fabsf(t0))) : 0.0f;
        float r1 = (t1 != 0.0f)
            ? __builtin_amdgcn_exp2f(bb * __builtin_amdgcn_logf(fabsf(t1))) : 0.0f;
        Sra += r0; Srb += r1;
        float c0 = (fk == idx) ? 1.0f : 0.0f;
        float val = __uint_as_float(tv << 16);
        float del = __uint_as_float(tv & 0xffff0000u);
        float c1 = fmaxf(fmaf(fr, del, val), 0.0f);
        S0a += c0; S1a = fmaf(r0, c0, S1a);
        S0b += c1; S1b = fmaf(r1, c1, S1b);
    };

    for (int base = 0; base < deg; base += 10) {
        int nchunk = deg - base; if (nchunk > 10) nchunk = 10;
        // clamped (branch-free) coalesced preload of this chunk's (dst,d)
        int idxc = off0 + base + ((fk < nchunk) ? fk : (nchunk - 1));
        int2 pk = csr_pk[idxc];
        int dstv = pk.x, dbits = pk.y;
        int jj = 0;
        for (; jj + 1 < nchunk; jj += 2) {
            int dA = __shfl(dstv, sub * 10 + jj, 64);
            int bA = __shfl(dbits, sub * 10 + jj, 64);
            int dB = __shfl(dstv, sub * 10 + jj + 1, 64);
            int bB = __shfl(dbits, sub * 10 + jj + 1, 64);
            process(dA, bA);
            process(dB, bB);
        }
        if (jj < nchunk) {
            int dA = __shfl(dstv, sub * 10 + jj, 64);
            int bA = __shfl(dbits, sub * 10 + jj, 64);
            process(dA, bA);
        }
    }

    float sf_lo = (S0a != 0.0f) ? (S1a / S0a) : (0.01f * Sra);
    float sf_hi = (S0b != 0.0f) ? (S1b / S0b) : (0.01f * Srb);

    if (active) {
        // epilogue: lane fk computes output rows fk and fk+10
        float acc0 = bias[fk];
        float acc1 = bias[fk + 10];
        const float* g1r0 = g1 + fk * HD;
        const float* g1r1 = g1 + (fk + 10) * HD;
        const float* g2r0 = g2 + fk * HD;
        const float* g2r1 = g2 + (fk + 10) * HD;
        #pragma unroll
        for (int j = 0; j < 10; ++j) {
            int sl = sub * 10 + j;
            float xj  = __shfl(xs_lo, sl, 64);
            float xj1 = __shfl(xs_hi, sl, 64);
            float sj  = __shfl(sf_lo, sl, 64);
            float sj1 = __shfl(sf_hi, sl, 64);
            acc0 = fmaf(xj, g1r0[j], acc0);  acc0 = fmaf(xj1, g1r0[j + 10], acc0);
            acc0 = fmaf(sj, g2r0[j], acc0);  acc0 = fmaf(sj1, g2r0[j + 10], acc0);
            acc1 = fmaf(xj, g1r1[j], acc1);  acc1 = fmaf(xj1, g1r1[j + 10], acc1);
            acc1 = fmaf(sj, g2r1[j], acc1);  acc1 = fmaf(sj1, g2r1[j + 10], acc1);
        }
        float* op = out + (size_t)node * 2 * HD;
        op[fk]          = fmaxf(acc0, 0.0f);
        op[fk + 10]     = fmaxf(acc1, 0.0f);
        op[HD + fk]     = sf_lo;
        op[HD + fk + 10] = sf_hi;
    }
}

extern "C" void kernel_launch(void* const* d_in, const int* in_sizes, int n_in,
                              void* d_out, int out_size, void* d_ws, size_t ws_size,
                              hipStream_t stream) {
    const float* x    = (const float*)d_in[0];
    const int*   ei   = (const int*)d_in[1];
    const float* ea   = (const float*)d_in[2];
    const float* pa   = (const float*)d_in[3];
    const float* pb   = (const float*)d_in[4];
    const float* g1   = (const float*)d_in[5];
    const float* g2   = (const float*)d_in[6];
    const float* bias = (const float*)d_in[7];
    const float* W1   = (const float*)d_in[8];
    const float* b1   = (const float*)d_in[9];
    const float* W2   = (const float*)d_in[10];
    const float* b2   = (const float*)d_in[11];
    float* out = (float*)d_out;

    // workspace layout (all segments 128B-aligned)
    char* ws = (char*)d_ws;
    int*   counts1 = (int*)ws;     ws += ((size_t)N1 * 4 + 127) / 128 * 128;
    int*   bsum1   = (int*)ws;     ws += (1024 * 4 + 127) / 128 * 128;
    int*   offsets = (int*)ws;     ws += ((size_t)(NN + 1) * 4 + 127) / 128 * 128;
    int2*  pk1     = (int2*)ws;    ws += (size_t)NE * 8;
    int2*  csr_pk  = (int2*)ws;    ws += (size_t)NE * 8;
    unsigned short* tab = (unsigned short*)ws;   ws += ((size_t)TBINS * 32 * 2 + 127) / 128 * 128;
    int*   xbf2    = (int*)ws;     ws += ((size_t)NN * 10 * 4 + 127) / 128 * 128;

    const int TBLK = (TBINS + 255) / 256;
    prep_kernel<<<TBLK + XBLK + NBLKS1, 256, 0, stream>>>(W1, b1, W2, b2, x, ei,
                                                          tab, xbf2, counts1);

    // pass 1: group by bucket (src>>9), LDS-sorted coalesced scatter
    const int nb1 = (N1 + 1023) / 1024;
    scan1_kernel<<<nb1, 1024, 0, stream>>>(counts1, bsum1, N1);
    scan3f_kernel<<<nb1, 1024, 0, stream>>>(counts1, bsum1, nb1, N1);
    scatter1_kernel<<<NBLKS1, 512, 0, stream>>>(ei, ea, counts1, pk1);

    // pass 2 fused: hist + scan + offsets + scatter, one block per bucket
    pass2_kernel<<<NBUCK, 1024, 0, stream>>>(pk1, counts1, offsets, csr_pk);

    node_kernel<<<(NN + 23) / 24, 256, 0, stream>>>(offsets, csr_pk, x, xbf2, tab,
                                                    pa, pb, g1, g2, bias, out);
}